// Round 1
// baseline (524.842 us; speedup 1.0000x reference)
//
#include <hip/hip_runtime.h>

#define Bc 1024
#define Tc 512
#define Ic 64
#define Hc 32

// K1: xp[b][t][h] = sum_i x[b][t][i] * W_ih[h][i] + b_ih[h]
// One thread per (b,t). x row (64 f) lives in registers; W_ih rows are
// wave-uniform loads (expect s_load). 2048 FMAs/thread, 4-way ILP via the
// unrolled 4-h group.
__global__ __launch_bounds__(256) void xproj_kernel(
    const float* __restrict__ x, const float* __restrict__ Wih,
    const float* __restrict__ bih, float* __restrict__ xp)
{
    const int gid = blockIdx.x * 256 + threadIdx.x;   // gid = b*T + t
    const float4* xrow = (const float4*)(x + (size_t)gid * Ic);
    float4 xv[16];
#pragma unroll
    for (int j = 0; j < 16; ++j) xv[j] = xrow[j];

    float4* xprow = (float4*)(xp + (size_t)gid * Hc);
#pragma unroll
    for (int hq = 0; hq < 8; ++hq) {
        float a[4];
#pragma unroll
        for (int r = 0; r < 4; ++r) {
            const int h = hq * 4 + r;
            const float4* wr = (const float4*)(Wih + h * Ic);
            float s = bih[h];
#pragma unroll
            for (int j = 0; j < 16; ++j) {
                float4 w = wr[j];
                s = fmaf(xv[j].x, w.x, s);
                s = fmaf(xv[j].y, w.y, s);
                s = fmaf(xv[j].z, w.z, s);
                s = fmaf(xv[j].w, w.w, s);
            }
            a[r] = s;
        }
        xprow[hq] = make_float4(a[0], a[1], a[2], a[3]);
    }
}

// K2: the sequential scan. 64 threads/block = 1 wave = 2 batch elements.
// lane = (half, h). h-state broadcast via 256 B LDS buffer (wave-private,
// but keep one barrier per step for safety). Out-projection folded in via
// shfl_xor butterfly over the 32-lane half.
__global__ __launch_bounds__(64) void rnn_kernel(
    const float* __restrict__ xp, const float* __restrict__ h0,
    const float* __restrict__ Whh, const float* __restrict__ bhh,
    const float* __restrict__ Wout, const float* __restrict__ bout,
    float* __restrict__ out)
{
    const int lane = threadIdx.x;
    const int half = lane >> 5;
    const int h    = lane & 31;
    const int b    = blockIdx.x * 2 + half;

    __shared__ __align__(16) float hbuf[2][32];

    float whh[Hc];
#pragma unroll
    for (int k = 0; k < Hc; ++k) whh[k] = Whh[h * Hc + k];
    const float bias = bhh[h];
    const float wo   = Wout[h];
    const float bo   = bout[0];

    float hval = h0[(size_t)b * Hc + h];

    const float* xprow = xp + (size_t)b * Tc * Hc + h;
    float* orow = out + (size_t)b * Tc;

    float xq = xprow[0];
    for (int t = 0; t < Tc; ++t) {
        const int tn = (t + 1 < Tc) ? (t + 1) : t;
        const float xq_next = xprow[(size_t)tn * Hc];  // prefetch next step

        hbuf[half][h] = hval;
        __syncthreads();

        float a0 = xq + bias, a1 = 0.f, a2 = 0.f, a3 = 0.f;
        const float4* hv = (const float4*)hbuf[half];
#pragma unroll
        for (int q = 0; q < 8; ++q) {
            float4 v = hv[q];
            a0 = fmaf(v.x, whh[q * 4 + 0], a0);
            a1 = fmaf(v.y, whh[q * 4 + 1], a1);
            a2 = fmaf(v.z, whh[q * 4 + 2], a2);
            a3 = fmaf(v.w, whh[q * 4 + 3], a3);
        }
        const float a = (a0 + a1) + (a2 + a3);

        // tanh(a) = 1 - 2/(exp2(a * 2*log2(e)) + 1); saturates correctly at +-inf
        const float p = exp2f(a * 2.8853900817779268f);
        const float r = __builtin_amdgcn_rcpf(p + 1.0f);
        hval = fmaf(-2.0f, r, 1.0f);

        // out[b][t] = sum_h Wout[h]*h_new[h] + bout  (butterfly within 32-lane half)
        float po = wo * hval;
        po += __shfl_xor(po, 1);
        po += __shfl_xor(po, 2);
        po += __shfl_xor(po, 4);
        po += __shfl_xor(po, 8);
        po += __shfl_xor(po, 16);
        if (h == 0) orow[t] = po + bo;

        xq = xq_next;
        __syncthreads();
    }

    // h_last: [1, B, H] appended after outs [B, T, 1]
    out[(size_t)Bc * Tc + (size_t)b * Hc + h] = hval;
}

extern "C" void kernel_launch(void* const* d_in, const int* in_sizes, int n_in,
                              void* d_out, int out_size, void* d_ws, size_t ws_size,
                              hipStream_t stream) {
    const float* x    = (const float*)d_in[0];
    const float* h0   = (const float*)d_in[1];
    const float* Wih  = (const float*)d_in[2];
    const float* bih  = (const float*)d_in[3];
    const float* Whh  = (const float*)d_in[4];
    const float* bhh  = (const float*)d_in[5];
    const float* Wout = (const float*)d_in[6];
    const float* bout = (const float*)d_in[7];
    float* out = (float*)d_out;
    float* xp  = (float*)d_ws;   // B*T*H fp32 = 64 MB scratch

    xproj_kernel<<<(Bc * Tc) / 256, 256, 0, stream>>>(x, Wih, bih, xp);
    rnn_kernel<<<Bc / 2, 64, 0, stream>>>(xp, h0, Whh, bhh, Wout, bout, out);
}